// Round 6
// baseline (683.877 us; speedup 1.0000x reference)
//
#include <hip/hip_runtime.h>

#define T_ 4
#define B_ 64
#define D_ 512
#define V_ 256

// ---- workspace byte offsets ----
// x splits, frag-linear: [bt 256][it 16][vg 16][lane 64][e 8] u16 (67.1 MB each)
#define XSH   0ull
#define XSM   67108864ull
#define XSL   134217728ull
// gate*k spikes, binary bf16, same frag-linear layout (67.1 MB)
#define OUTBT 201326592ull
// W splits frag-linear: (mat*3+s) arrays: [head 4][it 16][ip 8][lane 64][e 8]
#define WT    268435456ull
#define BNOF  273154048ull     // 6x512 floats

typedef unsigned short u16;
typedef __attribute__((ext_vector_type(8))) __bf16 bf16x8;
typedef __attribute__((ext_vector_type(4))) float f32x4;
typedef __attribute__((ext_vector_type(8))) unsigned short u16x8;
typedef __attribute__((ext_vector_type(4))) unsigned short u16x4;

__device__ __forceinline__ u16 f2bf(float f) {
    unsigned u = __float_as_uint(f);
    return (u16)((u + 0x7FFFu + ((u >> 16) & 1u)) >> 16);
}
__device__ __forceinline__ float bf2f(u16 h) {
    return __uint_as_float(((unsigned)h) << 16);
}

// async global->LDS DMA, 16B per lane. LDS dest must be wave-uniform base + lane*16.
#define GLL16(g, l) __builtin_amdgcn_global_load_lds( \
    (const __attribute__((address_space(1))) void*)(g), \
    (__attribute__((address_space(3))) void*)(l), 16, 0, 0)
#define WAITVM(n) asm volatile("s_waitcnt vmcnt(" #n ")" ::: "memory")
#define WAITLGKM() asm volatile("s_waitcnt lgkmcnt(0)" ::: "memory")

// ---------------------------------------------------------------------------
// prep: W 3-way bf16 splits in frag-linear layout + BN constants (unchanged).
// ---------------------------------------------------------------------------
__global__ __launch_bounds__(256) void k_prep2(
    const float* __restrict__ Wq, const float* __restrict__ Wk, const float* __restrict__ Wp,
    const float* __restrict__ qg, const float* __restrict__ qb,
    const float* __restrict__ qm, const float* __restrict__ qv,
    const float* __restrict__ kg, const float* __restrict__ kb,
    const float* __restrict__ km, const float* __restrict__ kv,
    const float* __restrict__ pg, const float* __restrict__ pb,
    const float* __restrict__ pm, const float* __restrict__ pv,
    char* __restrict__ ws)
{
    const int g = blockIdx.x * 256 + threadIdx.x;   // [0, 98304)
    const int mat = g >> 15;
    const int r = g & 32767;
    const int lane = r & 63;
    const int q = r >> 6;            // (head*16+it)*8+ip
    const int ip = q & 7;
    const int q2 = q >> 3;
    const int it = q2 & 15;
    const int head = q2 >> 4;
    const int row = head * 128 + ip * 16 + (lane & 15);
    const int kcol = it * 32 + (lane >> 4) * 8;
    const float* W = (mat == 0) ? Wq : (mat == 1 ? Wk : Wp);

    u16x8 h8, m8, l8;
#pragma unroll
    for (int e = 0; e < 8; ++e) {
        const float f = W[row * 512 + kcol + e];
        const u16 h = f2bf(f);          const float fh = bf2f(h);
        const u16 m = f2bf(f - fh);     const float fm = bf2f(m);
        const u16 l = f2bf(f - fh - fm);
        h8[e] = h; m8[e] = m; l8[e] = l;
    }
    u16* wt = (u16*)(ws + WT);
    const size_t o = (size_t)r * 8;
    *(u16x8*)(wt + (size_t)(mat * 3 + 0) * 262144 + o) = h8;
    *(u16x8*)(wt + (size_t)(mat * 3 + 1) * 262144 + o) = m8;
    *(u16x8*)(wt + (size_t)(mat * 3 + 2) * 262144 + o) = l8;

    if (g < 512) {
        float* bn = (float*)(ws + BNOF);
        float iv;
        iv = qg[g] * (1.0f / sqrtf(qv[g] + 1e-5f)); bn[g]        = iv; bn[512  + g] = qb[g] - qm[g] * iv;
        iv = kg[g] * (1.0f / sqrtf(kv[g] + 1e-5f)); bn[1024 + g] = iv; bn[1536 + g] = kb[g] - km[g] * iv;
        iv = pg[g] * (1.0f / sqrtf(pv[g] + 1e-5f)); bn[2048 + g] = iv; bn[2560 + g] = pb[g] - pm[g] * iv;
    }
}

// ---------------------------------------------------------------------------
// split_x: x (t,b,d,v) fp32 -> 3-way bf16 splits in frag-linear layout.
// ---------------------------------------------------------------------------
__global__ __launch_bounds__(256) void k_split_x2(
    const float* __restrict__ x, char* __restrict__ ws)
{
    const int bt = blockIdx.x >> 4;
    const int it = blockIdx.x & 15;
    const int tid = threadIdx.x;
#pragma unroll
    for (int r2 = 0; r2 < 4; ++r2) {
        const int slot = r2 * 256 + tid;       // 0..1023 = vg*64 + lane
        const int vg = slot >> 6;
        const int ll = slot & 63;
        const int v  = vg * 16 + (ll & 15);
        const int d0 = it * 32 + (ll >> 4) * 8;
        u16x8 h8, m8, l8;
#pragma unroll
        for (int e = 0; e < 8; ++e) {
            const float f = x[(size_t)bt * 131072 + (size_t)(d0 + e) * 256 + v];
            const u16 h = f2bf(f);          const float fh = bf2f(h);
            const u16 m = f2bf(f - fh);     const float fm = bf2f(m);
            const u16 lo = f2bf(f - fh - fm);
            h8[e] = h; m8[e] = m; l8[e] = lo;
        }
        const size_t o = (size_t)bt * 262144ull + (size_t)it * 16384ull
                       + (size_t)vg * 1024ull + (size_t)ll * 16ull;
        *(u16x8*)(ws + XSH + o) = h8;
        *(u16x8*)(ws + XSM + o) = m8;
        *(u16x8*)(ws + XSL + o) = l8;
    }
}

// ---------------------------------------------------------------------------
// Fused q+k, FLAT-STREAM 4-phase pipeline:
//  - (ph,t,it) flattened to 128 steps; DMA prefetch NEVER drains across t/ph
//    boundaries (only once per K-epilogue store burst, amortized by in-order
//    retirement + late-issue).
//  - per step, 4 j-phases; counted vmcnt(3)/(6) at exactly the phase that
//    first consumes each chunk; issue of next-step chunks spread p0/p1/p2;
//    setprio(1) around each MFMA cluster (T5).
//  - B staged in per-wave 1KB slices aligned to phase consumption.
//  - K-epilogue stores spikes DIRECT to global (same bytes the old LDS-tile
//    bounce produced) -> no tile alias, no syncthreads in epilogue.
//  - Q-epilogue uses raw s_barrier + lgkmcnt only (no vmcnt drain).
// ---------------------------------------------------------------------------
__global__ __launch_bounds__(512, 1) void k_qk2(char* __restrict__ ws)
{
    __shared__ char lds[150528];                 // buf0 72K | buf1 72K | qs 2K | gatef 4K
    float* qs    = (float*)(lds + 147456);       // [2][256]
    float* gatef = (float*)(lds + 149504);       // [4][256]

    const int tid  = threadIdx.x;
    const int lane = tid & 63;
    const int wave = tid >> 6;       // 0..7
    const int wr = wave >> 2;        // 0..1  (o half)
    const int wc = wave & 3;         // 0..3  (v quarter)
    const int quad = lane >> 4;
    const int l15  = lane & 15;
    const int to   = tid * 16;       // A staging: linear, uniform-base + lane*16
    // B chunk slices: chunk c covers j in {2c, 2c+1}; wave (wc, wr) covers
    // the 1KB at (wc*4 + c*2 + wr)*1024 (identity map global<->LDS).
    const int offB0 = (wc * 4 + 0 + wr) * 1024 + lane * 16;
    const int offB1 = (wc * 4 + 2 + wr) * 1024 + lane * 16;

    // XCD swizzle: 4 head-blocks of a b congruent mod 8 -> same XCD L2.
    const int xcd  = blockIdx.x & 7;
    const int slot = blockIdx.x >> 3;        // 0..31
    const int b    = xcd * 8 + (slot >> 2);
    const int head = slot & 3;

    constexpr int PA[6] = {0, 0, 1, 1, 0, 2};
    constexpr int PB[6] = {0, 1, 0, 1, 2, 0};

#define QK_ISSUE_A(gg, nb) { \
    const size_t wb_ = WT + (size_t)((gg) >> 6) * 1572864ull \
                     + (size_t)head * 131072ull + (size_t)((gg) & 15) * 8192ull; \
    _Pragma("unroll") \
    for (int s_ = 0; s_ < 3; ++s_) \
        GLL16(ws + wb_ + (size_t)s_ * 524288ull + to, (nb) + s_ * 8192 + to); }

#define QK_ISSUE_B(gg, nb, off) { \
    const size_t bb_ = (size_t)(((((gg) >> 4) & 3) * 64 + b)) * 262144ull \
                     + (size_t)((gg) & 15) * 16384ull; \
    _Pragma("unroll") \
    for (int s_ = 0; s_ < 3; ++s_) \
        GLL16(ws + (size_t)s_ * 67108864ull + bb_ + (off), (nb) + 24576 + s_ * 16384 + (off)); }

#define QK_DO_J(jq) { \
    bf16x8 bfr[3]; \
    _Pragma("unroll") \
    for (int s_ = 0; s_ < 3; ++s_) \
        bfr[s_] = *(const bf16x8*)(buf + 24576 + s_ * 16384 + (wc * 4 + (jq)) * 1024 + lane * 16); \
    __builtin_amdgcn_s_setprio(1); \
    _Pragma("unroll") \
    for (int i_ = 0; i_ < 4; ++i_) \
        _Pragma("unroll") \
        for (int p_ = 0; p_ < 6; ++p_) \
            acc[i_][jq] = __builtin_amdgcn_mfma_f32_16x16x32_bf16( \
                afr[PA[p_]][i_], bfr[PB[p_]], acc[i_][jq], 0, 0, 0); \
    __builtin_amdgcn_s_setprio(0); }

    f32x4 st[4][4], acc[4][4];
    float gstate = 0.f;

    // prologue: step 0 loads into buf0 (order: A, B0, B1)
    QK_ISSUE_A(0, lds);
    QK_ISSUE_B(0, lds, offB0);
    QK_ISSUE_B(0, lds, offB1);

#pragma unroll 1
    for (int g = 0; g < 128; ++g) {
        const int ph = g >> 6;
        const int t  = (g >> 4) & 3;
        const int it = g & 15;
        char* buf  = lds + (g & 1) * 73728;
        char* nbuf = lds + ((g + 1) & 1) * 73728;
        const bool kepi = (ph == 1) && (it == 15);   // K-epilogue step (has stores)
        const float* bn = (const float*)(ws + BNOF + (size_t)ph * 4096);

        if (it == 0) {
#pragma unroll
            for (int i = 0; i < 4; ++i)
#pragma unroll
                for (int j = 0; j < 4; ++j) {
                    acc[i][j] = (f32x4){0.f, 0.f, 0.f, 0.f};
                    if (t == 0) st[i][j] = (f32x4){0.f, 0.f, 0.f, 0.f};
                }
        }

        // ---- phase 0: consume A + B-chunk0 (j0) ----
        WAITVM(3);
        __builtin_amdgcn_s_barrier();
        if (!kepi) QK_ISSUE_A(g + 1, nbuf);
        bf16x8 afr[3][4];
#pragma unroll
        for (int s = 0; s < 3; ++s)
#pragma unroll
            for (int i = 0; i < 4; ++i)
                afr[s][i] = *(const bf16x8*)(buf + s * 8192 + wr * 4096
                                             + i * 1024 + lane * 16);
        QK_DO_J(0);
        // ---- phase 1: j1 (still chunk0) ----
        if (!kepi) QK_ISSUE_B(g + 1, nbuf, offB0);
        QK_DO_J(1);
        // ---- phase 2: consume B-chunk1 (j2) ----
        if (kepi) { WAITVM(0); } else { WAITVM(6); }
        __builtin_amdgcn_s_barrier();
        if (!kepi) QK_ISSUE_B(g + 1, nbuf, offB1);
        QK_DO_J(2);
        // ---- phase 3: j3 ----
        QK_DO_J(3);

        if (it == 15) {
            if (ph == 0) {
                // ---- phase Q epilogue: BN + LIF + per-column spike sums ----
                float qp[4] = {0.f, 0.f, 0.f, 0.f};
#pragma unroll
                for (int i = 0; i < 4; ++i) {
                    const int ob = head * 128 + wr * 64 + i * 16 + quad * 4;
                    const f32x4 inv = *(const f32x4*)(bn + ob);
                    const f32x4 add = *(const f32x4*)(bn + 512 + ob);
#pragma unroll
                    for (int j = 0; j < 4; ++j)
#pragma unroll
                        for (int r = 0; r < 4; ++r) {
                            const float y = acc[i][j][r] * inv[r] + add[r];
                            float v = (st[i][j][r] + y) * 0.5f;
                            const float s = (v >= 1.0f) ? 1.f : 0.f;
                            st[i][j][r] = (v >= 1.0f) ? 0.f : v;
                            qp[j] += s;
                        }
                }
#pragma unroll
                for (int j = 0; j < 4; ++j) {
                    qp[j] += __shfl_xor(qp[j], 16, 64);
                    qp[j] += __shfl_xor(qp[j], 32, 64);
                }
                if (quad == 0) {
#pragma unroll
                    for (int j = 0; j < 4; ++j)
                        qs[wr * 256 + wc * 64 + j * 16 + l15] = qp[j];
                }
                WAITLGKM();
                __builtin_amdgcn_s_barrier();
                if (tid < 256) {
                    const float qsum = qs[tid] + qs[256 + tid];
                    gstate = (gstate + qsum) * 0.5f;
                    const float gt = (gstate >= 0.5f) ? 1.f : 0.f;
                    gstate = (gstate >= 0.5f) ? 0.f : gstate;
                    gatef[t * 256 + tid] = gt;
                }
                WAITLGKM();
                __builtin_amdgcn_s_barrier();
            } else {
                // ---- K epilogue: BN + LIF + gate -> DIRECT global stores ----
                const int bt = t * 64 + b;
                const size_t dst = OUTBT + ((size_t)bt * 16ull + (size_t)head * 4ull) * 16384ull;
#pragma unroll
                for (int i = 0; i < 4; ++i) {
                    const int ob = head * 128 + wr * 64 + i * 16 + quad * 4;
                    const f32x4 inv = *(const f32x4*)(bn + ob);
                    const f32x4 add = *(const f32x4*)(bn + 512 + ob);
                    const int itL = wr * 2 + (i >> 1);
                    const int ls  = ((i & 1) * 2 + (quad >> 1)) * 16 + l15;
                    const int e0  = (quad & 1) * 4;
#pragma unroll
                    for (int j = 0; j < 4; ++j) {
                        const int col = wc * 64 + j * 16 + l15;
                        const float gt = gatef[t * 256 + col];
                        u16x4 w;
#pragma unroll
                        for (int r = 0; r < 4; ++r) {
                            const float y = acc[i][j][r] * inv[r] + add[r];
                            float v = (st[i][j][r] + y) * 0.5f;
                            const float s = (v >= 1.0f) ? 1.f : 0.f;
                            st[i][j][r] = (v >= 1.0f) ? 0.f : v;
                            w[r] = (s * gt != 0.f) ? (u16)0x3F80 : (u16)0;
                        }
                        *(u16x4*)(ws + dst
                            + (size_t)((itL * 16 + wc * 4 + j) * 64 + ls) * 16 + e0 * 2) = w;
                    }
                }
                // late-issue next step's loads behind the store burst
                if (g != 127) {
                    QK_ISSUE_A(g + 1, nbuf);
                    QK_ISSUE_B(g + 1, nbuf, offB0);
                    QK_ISSUE_B(g + 1, nbuf, offB1);
                }
            }
        }
    }
#undef QK_ISSUE_A
#undef QK_ISSUE_B
#undef QK_DO_J
}

// ---------------------------------------------------------------------------
// Fused p, FLAT-STREAM 4-phase pipeline (same schedule, 64 steps, 5 loads/step:
// A(3), Bchunk0(1), Bchunk1(1); waits vmcnt(1)/vmcnt(4)).
// ---------------------------------------------------------------------------
__global__ __launch_bounds__(512, 1) void k_p2(char* __restrict__ ws,
                                               float* __restrict__ out2)
{
    __shared__ char lds[81920];      // 2 x 40KB

    const int tid  = threadIdx.x;
    const int lane = tid & 63;
    const int wave = tid >> 6;
    const int wr = wave >> 2;
    const int wc = wave & 3;
    const int quad = lane >> 4;
    const int l15  = lane & 15;
    const int to   = tid * 16;
    const int offB0 = (wc * 4 + 0 + wr) * 1024 + lane * 16;
    const int offB1 = (wc * 4 + 2 + wr) * 1024 + lane * 16;

    const int xcd  = blockIdx.x & 7;
    const int slot = blockIdx.x >> 3;        // 0..31
    const int b  = xcd * 8 + (slot >> 2);
    const int ot = slot & 3;

    const float* bn = (const float*)(ws + BNOF + 8192);

#define P_ISSUE_A(gg, nb) { \
    const size_t wb_ = WT + 6ull * 524288ull + (size_t)ot * 131072ull \
                     + (size_t)((gg) & 15) * 8192ull; \
    _Pragma("unroll") \
    for (int s_ = 0; s_ < 3; ++s_) \
        GLL16(ws + wb_ + (size_t)s_ * 524288ull + to, (nb) + s_ * 8192 + to); }

#define P_ISSUE_B(gg, nb, off) { \
    const size_t bb_ = OUTBT + (size_t)((((gg) >> 4) * 64) + b) * 262144ull \
                     + (size_t)((gg) & 15) * 16384ull; \
    GLL16(ws + bb_ + (off), (nb) + 24576 + (off)); }

#define P_DO_J(jq) { \
    const bf16x8 bfr = *(const bf16x8*)(buf + 24576 + (wc * 4 + (jq)) * 1024 + lane * 16); \
    __builtin_amdgcn_s_setprio(1); \
    _Pragma("unroll") \
    for (int i_ = 0; i_ < 4; ++i_) \
        _Pragma("unroll") \
        for (int p_ = 0; p_ < 3; ++p_) \
            acc[i_][jq] = __builtin_amdgcn_mfma_f32_16x16x32_bf16( \
                afr[p_][i_], bfr, acc[i_][jq], 0, 0, 0); \
    __builtin_amdgcn_s_setprio(0); }

    f32x4 st[4][4], acc[4][4];

    P_ISSUE_A(0, lds);
    P_ISSUE_B(0, lds, offB0);
    P_ISSUE_B(0, lds, offB1);

#pragma unroll 1
    for (int g = 0; g < 64; ++g) {
        const int t  = g >> 4;
        const int it = g & 15;
        char* buf  = lds + (g & 1) * 40960;
        char* nbuf = lds + ((g + 1) & 1) * 40960;
        const bool kepi = (it == 15);

        if (it == 0) {
#pragma unroll
            for (int i = 0; i < 4; ++i)
#pragma unroll
                for (int j = 0; j < 4; ++j) {
                    acc[i][j] = (f32x4){0.f, 0.f, 0.f, 0.f};
                    if (g == 0) st[i][j] = (f32x4){0.f, 0.f, 0.f, 0.f};
                }
        }

        // ---- phase 0 ----
        WAITVM(1);
        __builtin_amdgcn_s_barrier();
        if (!kepi) P_ISSUE_A(g + 1, nbuf);
        bf16x8 afr[3][4];
#pragma unroll
        for (int s = 0; s < 3; ++s)
#pragma unroll
            for (int i = 0; i < 4; ++i)
                afr[s][i] = *(const bf16x8*)(buf + s * 8192 + wr * 4096
                                             + i * 1024 + lane * 16);
        P_DO_J(0);
        // ---- phase 1 ----
        if (!kepi) P_ISSUE_B(g + 1, nbuf, offB0);
        P_DO_J(1);
        // ---- phase 2 ----
        if (kepi) { WAITVM(0); } else { WAITVM(4); }
        __builtin_amdgcn_s_barrier();
        if (!kepi) P_ISSUE_B(g + 1, nbuf, offB1);
        P_DO_J(2);
        // ---- phase 3 ----
        P_DO_J(3);

        if (kepi) {
            // epilogue: BN + LIF step t, write spikes (T,B,D,V) fp32
#pragma unroll
            for (int i = 0; i < 4; ++i) {
                const int ob = ot * 128 + wr * 64 + i * 16 + quad * 4;
                const f32x4 inv = *(const f32x4*)(bn + ob);
                const f32x4 add = *(const f32x4*)(bn + 512 + ob);
#pragma unroll
                for (int j = 0; j < 4; ++j) {
                    const int col = wc * 64 + j * 16 + l15;
#pragma unroll
                    for (int r = 0; r < 4; ++r) {
                        const float y = acc[i][j][r] * inv[r] + add[r];
                        float v = (st[i][j][r] + y) * 0.5f;
                        const float s = (v >= 1.0f) ? 1.f : 0.f;
                        st[i][j][r] = (v >= 1.0f) ? 0.f : v;
                        out2[((size_t)(t * 64 + b) * 512 + ob + r) * 256 + col] = s;
                    }
                }
            }
            // late-issue next step's loads behind the store burst
            if (g != 63) {
                P_ISSUE_A(g + 1, nbuf);
                P_ISSUE_B(g + 1, nbuf, offB0);
                P_ISSUE_B(g + 1, nbuf, offB1);
            }
        }
    }
#undef P_ISSUE_A
#undef P_ISSUE_B
#undef P_DO_J
}

// ---------------------------------------------------------------------------
extern "C" void kernel_launch(void* const* d_in, const int* in_sizes, int n_in,
                              void* d_out, int out_size, void* d_ws, size_t ws_size,
                              hipStream_t stream)
{
    const float* x  = (const float*)d_in[0];
    const float* Wq = (const float*)d_in[1];
    const float* qg = (const float*)d_in[2];
    const float* qb = (const float*)d_in[3];
    const float* qm = (const float*)d_in[4];
    const float* qv = (const float*)d_in[5];
    const float* Wk = (const float*)d_in[6];
    const float* kg = (const float*)d_in[7];
    const float* kb = (const float*)d_in[8];
    const float* km = (const float*)d_in[9];
    const float* kv = (const float*)d_in[10];
    const float* Wp = (const float*)d_in[11];
    const float* pg = (const float*)d_in[12];
    const float* pb = (const float*)d_in[13];
    const float* pm = (const float*)d_in[14];
    const float* pv = (const float*)d_in[15];

    char* ws = (char*)d_ws;

    k_prep2<<<384, 256, 0, stream>>>(Wq, Wk, Wp, qg, qb, qm, qv,
                                     kg, kb, km, kv, pg, pb, pm, pv, ws);

    k_split_x2<<<4096, 256, 0, stream>>>(x, ws);

    k_qk2<<<256, 512, 0, stream>>>(ws);

    k_p2<<<256, 512, 0, stream>>>(ws, (float*)d_out);
}

// Round 7
// 647.389 us; speedup vs baseline: 1.0564x; 1.0564x over previous
//
#include <hip/hip_runtime.h>

#define T_ 4
#define B_ 64
#define D_ 512
#define V_ 256

// ---- workspace byte offsets ----
// x splits, frag-linear: [bt 256][it 16][vg 16][lane 64][e 8] u16 (67.1 MB each)
#define XSH   0ull
#define XSM   67108864ull
#define XSL   134217728ull
// gate*k spikes, binary bf16, same frag-linear layout (67.1 MB)
#define OUTBT 201326592ull
// W splits frag-linear: (mat*3+s) arrays: [head 4][it 16][ip 8][lane 64][e 8]
#define WT    268435456ull
#define BNOF  273154048ull     // 6x512 floats

typedef unsigned short u16;
typedef __attribute__((ext_vector_type(8))) __bf16 bf16x8;
typedef __attribute__((ext_vector_type(4))) float f32x4;
typedef __attribute__((ext_vector_type(8))) unsigned short u16x8;
typedef __attribute__((ext_vector_type(4))) unsigned short u16x4;

__device__ __forceinline__ u16 f2bf(float f) {
    unsigned u = __float_as_uint(f);
    return (u16)((u + 0x7FFFu + ((u >> 16) & 1u)) >> 16);
}
__device__ __forceinline__ float bf2f(u16 h) {
    return __uint_as_float(((unsigned)h) << 16);
}

// async global->LDS DMA, 16B per lane. LDS dest must be wave-uniform base + lane*16.
#define GLL16(g, l) __builtin_amdgcn_global_load_lds( \
    (const __attribute__((address_space(1))) void*)(g), \
    (__attribute__((address_space(3))) void*)(l), 16, 0, 0)
#define WAITVM(n) asm volatile("s_waitcnt vmcnt(" #n ")" ::: "memory")
#define WAITLGKM() asm volatile("s_waitcnt lgkmcnt(0)" ::: "memory")
#define BARRIER_MEM() asm volatile("s_barrier" ::: "memory")

// ---------------------------------------------------------------------------
// prep: W 3-way bf16 splits in frag-linear layout + BN constants (unchanged).
// ---------------------------------------------------------------------------
__global__ __launch_bounds__(256) void k_prep2(
    const float* __restrict__ Wq, const float* __restrict__ Wk, const float* __restrict__ Wp,
    const float* __restrict__ qg, const float* __restrict__ qb,
    const float* __restrict__ qm, const float* __restrict__ qv,
    const float* __restrict__ kg, const float* __restrict__ kb,
    const float* __restrict__ km, const float* __restrict__ kv,
    const float* __restrict__ pg, const float* __restrict__ pb,
    const float* __restrict__ pm, const float* __restrict__ pv,
    char* __restrict__ ws)
{
    const int g = blockIdx.x * 256 + threadIdx.x;   // [0, 98304)
    const int mat = g >> 15;
    const int r = g & 32767;
    const int lane = r & 63;
    const int q = r >> 6;            // (head*16+it)*8+ip
    const int ip = q & 7;
    const int q2 = q >> 3;
    const int it = q2 & 15;
    const int head = q2 >> 4;
    const int row = head * 128 + ip * 16 + (lane & 15);
    const int kcol = it * 32 + (lane >> 4) * 8;
    const float* W = (mat == 0) ? Wq : (mat == 1 ? Wk : Wp);

    u16x8 h8, m8, l8;
#pragma unroll
    for (int e = 0; e < 8; ++e) {
        const float f = W[row * 512 + kcol + e];
        const u16 h = f2bf(f);          const float fh = bf2f(h);
        const u16 m = f2bf(f - fh);     const float fm = bf2f(m);
        const u16 l = f2bf(f - fh - fm);
        h8[e] = h; m8[e] = m; l8[e] = l;
    }
    u16* wt = (u16*)(ws + WT);
    const size_t o = (size_t)r * 8;
    *(u16x8*)(wt + (size_t)(mat * 3 + 0) * 262144 + o) = h8;
    *(u16x8*)(wt + (size_t)(mat * 3 + 1) * 262144 + o) = m8;
    *(u16x8*)(wt + (size_t)(mat * 3 + 2) * 262144 + o) = l8;

    if (g < 512) {
        float* bn = (float*)(ws + BNOF);
        float iv;
        iv = qg[g] * (1.0f / sqrtf(qv[g] + 1e-5f)); bn[g]        = iv; bn[512  + g] = qb[g] - qm[g] * iv;
        iv = kg[g] * (1.0f / sqrtf(kv[g] + 1e-5f)); bn[1024 + g] = iv; bn[1536 + g] = kb[g] - km[g] * iv;
        iv = pg[g] * (1.0f / sqrtf(pv[g] + 1e-5f)); bn[2048 + g] = iv; bn[2560 + g] = pb[g] - pm[g] * iv;
    }
}

// ---------------------------------------------------------------------------
// split_x: x (t,b,d,v) fp32 -> 3-way bf16 splits in frag-linear layout.
// ---------------------------------------------------------------------------
__global__ __launch_bounds__(256) void k_split_x2(
    const float* __restrict__ x, char* __restrict__ ws)
{
    const int bt = blockIdx.x >> 4;
    const int it = blockIdx.x & 15;
    const int tid = threadIdx.x;
#pragma unroll
    for (int r2 = 0; r2 < 4; ++r2) {
        const int slot = r2 * 256 + tid;       // 0..1023 = vg*64 + lane
        const int vg = slot >> 6;
        const int ll = slot & 63;
        const int v  = vg * 16 + (ll & 15);
        const int d0 = it * 32 + (ll >> 4) * 8;
        u16x8 h8, m8, l8;
#pragma unroll
        for (int e = 0; e < 8; ++e) {
            const float f = x[(size_t)bt * 131072 + (size_t)(d0 + e) * 256 + v];
            const u16 h = f2bf(f);          const float fh = bf2f(h);
            const u16 m = f2bf(f - fh);     const float fm = bf2f(m);
            const u16 lo = f2bf(f - fh - fm);
            h8[e] = h; m8[e] = m; l8[e] = lo;
        }
        const size_t o = (size_t)bt * 262144ull + (size_t)it * 16384ull
                       + (size_t)vg * 1024ull + (size_t)ll * 16ull;
        *(u16x8*)(ws + XSH + o) = h8;
        *(u16x8*)(ws + XSM + o) = m8;
        *(u16x8*)(ws + XSL + o) = l8;
    }
}

// ---------------------------------------------------------------------------
// Fused q+k, FLAT-STREAM 4-phase pipeline v7:
//  - (ph,t,it) flattened to 128 steps; prefetch NEVER drains (counted vmcnt
//    only; vmcnt(0) solely at the final step where no newer loads exist).
//  - issues at normal phase positions at EVERY step (incl. epilogue steps).
//  - NO setprio (m190 + round-6: negative in barrier-lockstep blocks).
//  - K-epilogue: coalesced LDS-tile store path restored; tile lives in the
//    just-consumed buf (prefetch targets nbuf -> no collision, no drain).
// ---------------------------------------------------------------------------
__global__ __launch_bounds__(512, 1) void k_qk2(char* __restrict__ ws)
{
    __shared__ char lds[150528];                 // buf0 72K | buf1 72K | qs 2K | gatef 4K
    float* qs    = (float*)(lds + 147456);       // [2][256]
    float* gatef = (float*)(lds + 149504);       // [4][256]

    const int tid  = threadIdx.x;
    const int lane = tid & 63;
    const int wave = tid >> 6;       // 0..7
    const int wr = wave >> 2;        // 0..1  (o half)
    const int wc = wave & 3;         // 0..3  (v quarter)
    const int quad = lane >> 4;
    const int l15  = lane & 15;
    const int to   = tid * 16;       // A staging: linear, uniform-base + lane*16
    // B chunk slices: chunk c covers j in {2c, 2c+1}; wave (wc, wr) stages
    // the 1KB at (wc*4 + c*2 + wr)*1024 (identity map global<->LDS).
    const int offB0 = (wc * 4 + 0 + wr) * 1024 + lane * 16;
    const int offB1 = (wc * 4 + 2 + wr) * 1024 + lane * 16;

    // XCD swizzle: 4 head-blocks of a b congruent mod 8 -> same XCD L2.
    const int xcd  = blockIdx.x & 7;
    const int slot = blockIdx.x >> 3;        // 0..31
    const int b    = xcd * 8 + (slot >> 2);
    const int head = slot & 3;

    constexpr int PA[6] = {0, 0, 1, 1, 0, 2};
    constexpr int PB[6] = {0, 1, 0, 1, 2, 0};

#define QK_ISSUE_A(gg, nb) { \
    const size_t wb_ = WT + (size_t)((gg) >> 6) * 1572864ull \
                     + (size_t)head * 131072ull + (size_t)((gg) & 15) * 8192ull; \
    _Pragma("unroll") \
    for (int s_ = 0; s_ < 3; ++s_) \
        GLL16(ws + wb_ + (size_t)s_ * 524288ull + to, (nb) + s_ * 8192 + to); }

#define QK_ISSUE_B(gg, nb, off) { \
    const size_t bb_ = (size_t)(((((gg) >> 4) & 3) * 64 + b)) * 262144ull \
                     + (size_t)((gg) & 15) * 16384ull; \
    _Pragma("unroll") \
    for (int s_ = 0; s_ < 3; ++s_) \
        GLL16(ws + (size_t)s_ * 67108864ull + bb_ + (off), (nb) + 24576 + s_ * 16384 + (off)); }

#define QK_DO_J(jq) { \
    bf16x8 bfr[3]; \
    _Pragma("unroll") \
    for (int s_ = 0; s_ < 3; ++s_) \
        bfr[s_] = *(const bf16x8*)(buf + 24576 + s_ * 16384 + (wc * 4 + (jq)) * 1024 + lane * 16); \
    _Pragma("unroll") \
    for (int i_ = 0; i_ < 4; ++i_) \
        _Pragma("unroll") \
        for (int p_ = 0; p_ < 6; ++p_) \
            acc[i_][jq] = __builtin_amdgcn_mfma_f32_16x16x32_bf16( \
                afr[PA[p_]][i_], bfr[PB[p_]], acc[i_][jq], 0, 0, 0); }

    f32x4 st[4][4], acc[4][4];
    float gstate = 0.f;

    // prologue: step 0 loads into buf0 (order: A, B0, B1)
    QK_ISSUE_A(0, lds);
    QK_ISSUE_B(0, lds, offB0);
    QK_ISSUE_B(0, lds, offB1);

#pragma unroll 1
    for (int g = 0; g < 128; ++g) {
        const int ph = g >> 6;
        const int t  = (g >> 4) & 3;
        const int it = g & 15;
        char* buf  = lds + (g & 1) * 73728;
        char* nbuf = lds + ((g + 1) & 1) * 73728;
        const bool last = (g == 127);
        const float* bn = (const float*)(ws + BNOF + (size_t)ph * 4096);

        if (it == 0) {
#pragma unroll
            for (int i = 0; i < 4; ++i)
#pragma unroll
                for (int j = 0; j < 4; ++j) {
                    acc[i][j] = (f32x4){0.f, 0.f, 0.f, 0.f};
                    if (t == 0) st[i][j] = (f32x4){0.f, 0.f, 0.f, 0.f};
                }
        }

        // ---- phase 0: consume A + B-chunk0 (j0) ----
        WAITVM(3);
        __builtin_amdgcn_s_barrier();
        if (!last) QK_ISSUE_A(g + 1, nbuf);
        bf16x8 afr[3][4];
#pragma unroll
        for (int s = 0; s < 3; ++s)
#pragma unroll
            for (int i = 0; i < 4; ++i)
                afr[s][i] = *(const bf16x8*)(buf + s * 8192 + wr * 4096
                                             + i * 1024 + lane * 16);
        QK_DO_J(0);
        // ---- phase 1: j1 (still chunk0) ----
        if (!last) QK_ISSUE_B(g + 1, nbuf, offB0);
        QK_DO_J(1);
        // ---- phase 2: consume B-chunk1 (j2) ----
        if (last) { WAITVM(0); } else { WAITVM(6); }
        __builtin_amdgcn_s_barrier();
        if (!last) QK_ISSUE_B(g + 1, nbuf, offB1);
        QK_DO_J(2);
        // ---- phase 3: j3 ----
        QK_DO_J(3);

        if (it == 15) {
            if (ph == 0) {
                // ---- phase Q epilogue: BN + LIF + per-column spike sums ----
                float qp[4] = {0.f, 0.f, 0.f, 0.f};
#pragma unroll
                for (int i = 0; i < 4; ++i) {
                    const int ob = head * 128 + wr * 64 + i * 16 + quad * 4;
                    const f32x4 inv = *(const f32x4*)(bn + ob);
                    const f32x4 add = *(const f32x4*)(bn + 512 + ob);
#pragma unroll
                    for (int j = 0; j < 4; ++j)
#pragma unroll
                        for (int r = 0; r < 4; ++r) {
                            const float y = acc[i][j][r] * inv[r] + add[r];
                            float v = (st[i][j][r] + y) * 0.5f;
                            const float s = (v >= 1.0f) ? 1.f : 0.f;
                            st[i][j][r] = (v >= 1.0f) ? 0.f : v;
                            qp[j] += s;
                        }
                }
#pragma unroll
                for (int j = 0; j < 4; ++j) {
                    qp[j] += __shfl_xor(qp[j], 16, 64);
                    qp[j] += __shfl_xor(qp[j], 32, 64);
                }
                if (quad == 0) {
#pragma unroll
                    for (int j = 0; j < 4; ++j)
                        qs[wr * 256 + wc * 64 + j * 16 + l15] = qp[j];
                }
                WAITLGKM();
                __builtin_amdgcn_s_barrier();
                if (tid < 256) {
                    const float qsum = qs[tid] + qs[256 + tid];
                    gstate = (gstate + qsum) * 0.5f;
                    const float gt = (gstate >= 0.5f) ? 1.f : 0.f;
                    gstate = (gstate >= 0.5f) ? 0.f : gstate;
                    gatef[t * 256 + tid] = gt;
                }
                WAITLGKM();
                __builtin_amdgcn_s_barrier();
            } else {
                // ---- K epilogue: BN + LIF + gate -> tile in consumed buf,
                //      then coalesced global stores. Prefetch stays in flight
                //      (it targets nbuf).
                u16* tile = (u16*)buf;
                BARRIER_MEM();                    // all reads of buf done
#pragma unroll
                for (int i = 0; i < 4; ++i) {
                    const int ob = head * 128 + wr * 64 + i * 16 + quad * 4;
                    const f32x4 inv = *(const f32x4*)(bn + ob);
                    const f32x4 add = *(const f32x4*)(bn + 512 + ob);
                    const int itL = wr * 2 + (i >> 1);
                    const int ls  = ((i & 1) * 2 + (quad >> 1)) * 16 + l15;
                    const int e0  = (quad & 1) * 4;
#pragma unroll
                    for (int j = 0; j < 4; ++j) {
                        const int col = wc * 64 + j * 16 + l15;
                        const float gt = gatef[t * 256 + col];
                        u16x4 w;
#pragma unroll
                        for (int r = 0; r < 4; ++r) {
                            const float y = acc[i][j][r] * inv[r] + add[r];
                            float v = (st[i][j][r] + y) * 0.5f;
                            const float s = (v >= 1.0f) ? 1.f : 0.f;
                            st[i][j][r] = (v >= 1.0f) ? 0.f : v;
                            w[r] = (s * gt != 0.f) ? (u16)0x3F80 : (u16)0;
                        }
                        *(u16x4*)&tile[(size_t)((itL * 16 + wc * 4 + j) * 64 + ls) * 8 + e0] = w;
                    }
                }
                WAITLGKM();
                BARRIER_MEM();                    // tile complete
                const int bt = t * 64 + b;
                const size_t dst = OUTBT + ((size_t)bt * 16ull + (size_t)head * 4ull) * 16384ull;
#pragma unroll
                for (int c = 0; c < 8; ++c) {
                    const int idx = c * 512 + tid;   // float4 units, 0..4095
                    *(float4*)(ws + dst + (size_t)idx * 16) = *(const float4*)&tile[(size_t)idx * 8];
                }
                BARRIER_MEM();                    // tile reads done before buf restaged
            }
        }
    }
#undef QK_ISSUE_A
#undef QK_ISSUE_B
#undef QK_DO_J
}

// ---------------------------------------------------------------------------
// Fused p, FLAT-STREAM 4-phase pipeline v7 (64 steps, 5 loads/step:
// A(3), Bchunk0(1), Bchunk1(1); waits vmcnt(1)/vmcnt(4); no setprio;
// issues at normal positions every step; vmcnt(0) only at the final step).
// ---------------------------------------------------------------------------
__global__ __launch_bounds__(512, 1) void k_p2(char* __restrict__ ws,
                                               float* __restrict__ out2)
{
    __shared__ char lds[81920];      // 2 x 40KB

    const int tid  = threadIdx.x;
    const int lane = tid & 63;
    const int wave = tid >> 6;
    const int wr = wave >> 2;
    const int wc = wave & 3;
    const int quad = lane >> 4;
    const int l15  = lane & 15;
    const int to   = tid * 16;
    const int offB0 = (wc * 4 + 0 + wr) * 1024 + lane * 16;
    const int offB1 = (wc * 4 + 2 + wr) * 1024 + lane * 16;

    const int xcd  = blockIdx.x & 7;
    const int slot = blockIdx.x >> 3;        // 0..31
    const int b  = xcd * 8 + (slot >> 2);
    const int ot = slot & 3;

    const float* bn = (const float*)(ws + BNOF + 8192);

#define P_ISSUE_A(gg, nb) { \
    const size_t wb_ = WT + 6ull * 524288ull + (size_t)ot * 131072ull \
                     + (size_t)((gg) & 15) * 8192ull; \
    _Pragma("unroll") \
    for (int s_ = 0; s_ < 3; ++s_) \
        GLL16(ws + wb_ + (size_t)s_ * 524288ull + to, (nb) + s_ * 8192 + to); }

#define P_ISSUE_B(gg, nb, off) { \
    const size_t bb_ = OUTBT + (size_t)((((gg) >> 4) * 64) + b) * 262144ull \
                     + (size_t)((gg) & 15) * 16384ull; \
    GLL16(ws + bb_ + (off), (nb) + 24576 + (off)); }

#define P_DO_J(jq) { \
    const bf16x8 bfr = *(const bf16x8*)(buf + 24576 + (wc * 4 + (jq)) * 1024 + lane * 16); \
    _Pragma("unroll") \
    for (int i_ = 0; i_ < 4; ++i_) \
        _Pragma("unroll") \
        for (int p_ = 0; p_ < 3; ++p_) \
            acc[i_][jq] = __builtin_amdgcn_mfma_f32_16x16x32_bf16( \
                afr[p_][i_], bfr, acc[i_][jq], 0, 0, 0); }

    f32x4 st[4][4], acc[4][4];

    P_ISSUE_A(0, lds);
    P_ISSUE_B(0, lds, offB0);
    P_ISSUE_B(0, lds, offB1);

#pragma unroll 1
    for (int g = 0; g < 64; ++g) {
        const int t  = g >> 4;
        const int it = g & 15;
        char* buf  = lds + (g & 1) * 40960;
        char* nbuf = lds + ((g + 1) & 1) * 40960;
        const bool last = (g == 63);

        if (it == 0) {
#pragma unroll
            for (int i = 0; i < 4; ++i)
#pragma unroll
                for (int j = 0; j < 4; ++j) {
                    acc[i][j] = (f32x4){0.f, 0.f, 0.f, 0.f};
                    if (g == 0) st[i][j] = (f32x4){0.f, 0.f, 0.f, 0.f};
                }
        }

        // ---- phase 0 ----
        WAITVM(1);
        __builtin_amdgcn_s_barrier();
        if (!last) P_ISSUE_A(g + 1, nbuf);
        bf16x8 afr[3][4];
#pragma unroll
        for (int s = 0; s < 3; ++s)
#pragma unroll
            for (int i = 0; i < 4; ++i)
                afr[s][i] = *(const bf16x8*)(buf + s * 8192 + wr * 4096
                                             + i * 1024 + lane * 16);
        P_DO_J(0);
        // ---- phase 1 ----
        if (!last) P_ISSUE_B(g + 1, nbuf, offB0);
        P_DO_J(1);
        // ---- phase 2 ----
        if (last) { WAITVM(0); } else { WAITVM(4); }
        __builtin_amdgcn_s_barrier();
        if (!last) P_ISSUE_B(g + 1, nbuf, offB1);
        P_DO_J(2);
        // ---- phase 3 ----
        P_DO_J(3);

        if (it == 15) {
            // epilogue: BN + LIF step t, write spikes (T,B,D,V) fp32
#pragma unroll
            for (int i = 0; i < 4; ++i) {
                const int ob = ot * 128 + wr * 64 + i * 16 + quad * 4;
                const f32x4 inv = *(const f32x4*)(bn + ob);
                const f32x4 add = *(const f32x4*)(bn + 512 + ob);
#pragma unroll
                for (int j = 0; j < 4; ++j) {
                    const int col = wc * 64 + j * 16 + l15;
#pragma unroll
                    for (int r = 0; r < 4; ++r) {
                        const float y = acc[i][j][r] * inv[r] + add[r];
                        float v = (st[i][j][r] + y) * 0.5f;
                        const float s = (v >= 1.0f) ? 1.f : 0.f;
                        st[i][j][r] = (v >= 1.0f) ? 0.f : v;
                        out2[((size_t)(t * 64 + b) * 512 + ob + r) * 256 + col] = s;
                    }
                }
            }
        }
    }
#undef P_ISSUE_A
#undef P_ISSUE_B
#undef P_DO_J
}

// ---------------------------------------------------------------------------
extern "C" void kernel_launch(void* const* d_in, const int* in_sizes, int n_in,
                              void* d_out, int out_size, void* d_ws, size_t ws_size,
                              hipStream_t stream)
{
    const float* x  = (const float*)d_in[0];
    const float* Wq = (const float*)d_in[1];
    const float* qg = (const float*)d_in[2];
    const float* qb = (const float*)d_in[3];
    const float* qm = (const float*)d_in[4];
    const float* qv = (const float*)d_in[5];
    const float* Wk = (const float*)d_in[6];
    const float* kg = (const float*)d_in[7];
    const float* kb = (const float*)d_in[8];
    const float* km = (const float*)d_in[9];
    const float* kv = (const float*)d_in[10];
    const float* Wp = (const float*)d_in[11];
    const float* pg = (const float*)d_in[12];
    const float* pb = (const float*)d_in[13];
    const float* pm = (const float*)d_in[14];
    const float* pv = (const float*)d_in[15];

    char* ws = (char*)d_ws;

    k_prep2<<<384, 256, 0, stream>>>(Wq, Wk, Wp, qg, qb, qm, qv,
                                     kg, kb, km, kv, pg, pb, pm, pv, ws);

    k_split_x2<<<4096, 256, 0, stream>>>(x, ws);

    k_qk2<<<256, 512, 0, stream>>>(ws);

    k_p2<<<256, 512, 0, stream>>>(ws, (float*)d_out);
}